// Round 8
// baseline (454.979 us; speedup 1.0000x reference)
//
#include <hip/hip_runtime.h>
#include <math.h>

#define HEADS   16
#define DHEAD   64
#define SEQ     2048
#define NB      2
#define DM      1024
#define NTOK    4096           // NB*SEQ
#define WEPS    1e-5

using f16x8   = __attribute__((ext_vector_type(8))) _Float16;
using f16x4   = __attribute__((ext_vector_type(4))) _Float16;
using floatx4 = __attribute__((ext_vector_type(4))) float;
using i32x4   = __attribute__((ext_vector_type(4))) int;

typedef __attribute__((address_space(1))) unsigned int gu32;
typedef __attribute__((address_space(3))) unsigned int lu32;

// lgkmcnt(0)-only barrier: does NOT drain vmcnt (register prefetch survives).
// Safe because LDS staging here is plain ds_write (not global_load_lds DMA).
#define BAR_LGKM()  asm volatile("s_waitcnt lgkmcnt(0)\n\ts_barrier" ::: "memory")
#define WAIT_LGKM() asm volatile("s_waitcnt lgkmcnt(0)" ::: "memory")

__device__ __forceinline__ unsigned pack2(_Float16 a, _Float16 b) {
    union { _Float16 h[2]; unsigned u; } c; c.h[0] = a; c.h[1] = b; return c.u;
}
__device__ __forceinline__ _Float16 lo16(unsigned u) {
    union { unsigned u; _Float16 h[2]; } c; c.u = u; return c.h[0];
}
__device__ __forceinline__ _Float16 hi16(unsigned u) {
    union { unsigned u; _Float16 h[2]; } c; c.u = u; return c.h[1];
}
__device__ __forceinline__ unsigned short h16b(_Float16 h) {
    union { _Float16 h; unsigned short u; } c; c.h = h; return c.u;
}

// ---------------- weight |w| mean: pass 1 (partial sums in double) ----------------
__global__ void wsum1(const float* __restrict__ w0, const float* __restrict__ w1,
                      const float* __restrict__ w2, const float* __restrict__ w3,
                      double* __restrict__ partial) {
    const float* w = (blockIdx.y == 0) ? w0 : (blockIdx.y == 1) ? w1 : (blockIdx.y == 2) ? w2 : w3;
    int base = blockIdx.x * 16384;
    double s = 0.0;
    for (int i = threadIdx.x; i < 16384; i += 256)
        s += fabs((double)w[base + i]);
    __shared__ double sd[256];
    sd[threadIdx.x] = s;
    __syncthreads();
    for (int st = 128; st > 0; st >>= 1) {
        if (threadIdx.x < st) sd[threadIdx.x] += sd[threadIdx.x + st];
        __syncthreads();
    }
    if (threadIdx.x == 0) partial[blockIdx.y * 64 + blockIdx.x] = sd[0];
}

// ---------------- weight mean: pass 2 -> wscale[w] = clip(mean|w|, eps) ----------------
__global__ void wsum2(const double* __restrict__ partial, double* __restrict__ wscale) {
    int t = threadIdx.x;
    if (t < 4) {
        double s = 0.0;
        for (int i = 0; i < 64; i++) s += partial[t * 64 + i];
        double mean = s / (1024.0 * 1024.0);
        wscale[t] = (mean > WEPS) ? mean : WEPS;
    }
}

// ---------------- ternary weight quant -> int8 {-1,0,1} ----------------
__global__ void wquant(const float* __restrict__ w0, const float* __restrict__ w1,
                       const float* __restrict__ w2, const float* __restrict__ w3,
                       const double* __restrict__ wscale, signed char* __restrict__ wq) {
    int widx = blockIdx.y;
    const float* w = (widx == 0) ? w0 : (widx == 1) ? w1 : (widx == 2) ? w2 : w3;
    double ws = 1.0 / wscale[widx];
    int idx = (blockIdx.x * 256 + threadIdx.x) * 4;
    float4 wv = *(const float4*)(w + idx);
    char4 o;
    {
        double r = rint((double)wv.x * ws); r = r > 1.0 ? 1.0 : (r < -1.0 ? -1.0 : r); o.x = (signed char)r;
    } {
        double r = rint((double)wv.y * ws); r = r > 1.0 ? 1.0 : (r < -1.0 ? -1.0 : r); o.y = (signed char)r;
    } {
        double r = rint((double)wv.z * ws); r = r > 1.0 ? 1.0 : (r < -1.0 ? -1.0 : r); o.z = (signed char)r;
    } {
        double r = rint((double)wv.w * ws); r = r > 1.0 ? 1.0 : (r < -1.0 ? -1.0 : r); o.w = (signed char)r;
    }
    *(char4*)(wq + (size_t)widx * 1048576 + idx) = o;
}

// ---------------- per-token int8 absmax activation quant -> int8 ----------------
__device__ __forceinline__ void aquant_row(const float* __restrict__ row,
                                           signed char* __restrict__ dst_row,
                                           double* __restrict__ ascale_p) {
    int t = threadIdx.x;
    float4 xv = *(const float4*)(row + t * 4);
    float a = fmaxf(fmaxf(fabsf(xv.x), fabsf(xv.y)), fmaxf(fabsf(xv.z), fabsf(xv.w)));
    __shared__ float sm[256];
    sm[t] = a;
    __syncthreads();
    for (int st = 128; st > 0; st >>= 1) {
        if (t < st) sm[t] = fmaxf(sm[t], sm[t + st]);
        __syncthreads();
    }
    double mx = (double)sm[0];
    if (mx < WEPS) mx = WEPS;
    if (t == 0) *ascale_p = mx / 127.0;
    double xs = 127.0 / mx;
    char4 o;
    {
        double r = rint((double)xv.x * xs); r = r > 127.0 ? 127.0 : (r < -128.0 ? -128.0 : r); o.x = (signed char)r;
    } {
        double r = rint((double)xv.y * xs); r = r > 127.0 ? 127.0 : (r < -128.0 ? -128.0 : r); o.y = (signed char)r;
    } {
        double r = rint((double)xv.z * xs); r = r > 127.0 ? 127.0 : (r < -128.0 ? -128.0 : r); o.z = (signed char)r;
    } {
        double r = rint((double)xv.w * xs); r = r > 127.0 ? 127.0 : (r < -128.0 ? -128.0 : r); o.w = (signed char)r;
    }
    *(char4*)(dst_row + t * 4) = o;
}

__global__ void aquant(const float* __restrict__ src, signed char* __restrict__ dst,
                       double* __restrict__ ascale) {
    int tok = blockIdx.x;
    aquant_row(src + (size_t)tok * DM, dst + (size_t)tok * DM, ascale + tok);
}

// fused x + context quant: xq/cq and ascale_x/ascale_c are contiguous in ws
__global__ void aquant2(const float* __restrict__ x, const float* __restrict__ ctx,
                        signed char* __restrict__ dst, double* __restrict__ ascale) {
    int tok = blockIdx.x;
    const float* row = (tok < NTOK) ? x + (size_t)tok * DM : ctx + (size_t)(tok - NTOK) * DM;
    aquant_row(row, dst + (size_t)tok * DM, ascale + tok);
}

// ---------------- int8 MFMA GEMM core: C[m][n] = sum_k A[m][k]*W[n][k], exact i32 ----------
// m97 structure: async global_load_lds width-16 staging, 128x128 tile, BK=64.
// mode 0: write SEPARATE hi/lo f16 limb planes at [b][h][t][dh]
//         (hi = (f16)(val*prescale), lo = (f16)((v-hi)*2048); lo plane at +4194304 elems)
// mode 2: packed (hi,lo) u32 words at [b][h][dh][t]  (V transposed, attn B-fragment-ready)
// mode 1: plain fp32 [t][o].
__device__ __forceinline__ void gemm_core(
        const signed char* __restrict__ A, const signed char* __restrict__ W,
        const double* __restrict__ ascale, double wsc,
        void* __restrict__ outp, int mode, float prescale, int bx, int by) {
    __shared__ __align__(16) signed char lds_a[128 * 64];
    __shared__ __align__(16) signed char lds_b[128 * 64];
    const int tid  = threadIdx.x;
    const int wave = tid >> 6, lane = tid & 63;
    const int wr = wave >> 1, wc = wave & 1;
    const int quad = lane >> 4, l15 = lane & 15;
    const int row0 = by * 128, col0 = bx * 128;
    i32x4 acc[4][4] = {};

    const signed char* ga0 = A + (size_t)(row0 + (lane >> 2)) * DM + (lane & 3) * 16;
    const signed char* gb0 = W + (size_t)(col0 + (lane >> 2)) * DM + (lane & 3) * 16;

    for (int k0 = 0; k0 < DM; k0 += 64) {
        __syncthreads();
        #pragma unroll
        for (int t = 0; t < 2; t++) {
            const int i = wave + t * 4;                 // wave-uniform instr index, 8 total
            __builtin_amdgcn_global_load_lds(
                (const gu32*)(const void*)(ga0 + (size_t)i * 16 * DM + k0),
                (lu32*)(void*)(lds_a + i * 1024), 16, 0, 0);
            __builtin_amdgcn_global_load_lds(
                (const gu32*)(const void*)(gb0 + (size_t)i * 16 * DM + k0),
                (lu32*)(void*)(lds_b + i * 1024), 16, 0, 0);
        }
        __syncthreads();
        i32x4 af[4], bfr[4];
        #pragma unroll
        for (int mi = 0; mi < 4; mi++) {
            int r = wr * 64 + mi * 16 + l15;
            af[mi] = *(const i32x4*)&lds_a[r * 64 + quad * 16];
        }
        #pragma unroll
        for (int ni = 0; ni < 4; ni++) {
            int n = wc * 64 + ni * 16 + l15;
            bfr[ni] = *(const i32x4*)&lds_b[n * 64 + quad * 16];
        }
        #pragma unroll
        for (int mi = 0; mi < 4; mi++)
            #pragma unroll
            for (int ni = 0; ni < 4; ni++)
                acc[mi][ni] = __builtin_amdgcn_mfma_i32_16x16x64_i8(af[mi], bfr[ni], acc[mi][ni], 0, 0, 0);
    }

    #pragma unroll
    for (int mi = 0; mi < 4; mi++) {
        int tbase = row0 + wr * 64 + mi * 16 + quad * 4;
        #pragma unroll
        for (int reg = 0; reg < 4; reg++) {
            int t = tbase + reg;
            double sa = ascale[t] * wsc;
            #pragma unroll
            for (int ni = 0; ni < 4; ni++) {
                int o = col0 + wc * 64 + ni * 16 + l15;
                float val = (float)((double)acc[mi][ni][reg] * sa);
                if (mode == 1) {
                    ((float*)outp)[(size_t)t * DM + o] = val;
                } else {
                    int bb = t >> 11, n = t & 2047, hh = o >> 6, dh = o & 63;
                    float fv = val * prescale;
                    _Float16 hl = (_Float16)fv;
                    _Float16 ml = (_Float16)((fv - (float)hl) * 2048.0f);
                    if (mode == 0) {
                        size_t idx = (((size_t)(bb * HEADS + hh) * SEQ + n) << 6) + dh;
                        ((unsigned short*)outp)[idx]           = h16b(hl);
                        ((unsigned short*)outp)[idx + 4194304] = h16b(ml);
                    } else {  // mode 2: V transposed [b][h][dh][t], packed word
                        ((unsigned*)outp)[(((size_t)(bb * HEADS + hh) * 64 + dh) << 11) + n] = pack2(hl, ml);
                    }
                }
            }
        }
    }
}

// fused Q/K/V projections: 768 blocks = 3/CU co-resident (hides barrier drain)
// Q prescale folds softmax scale AND log2(e): 0.125 * 1.4426950408889634
__global__ __launch_bounds__(256) void gemm_qkv(
        const signed char* __restrict__ xq, const signed char* __restrict__ cq,
        const signed char* __restrict__ wqb, const double* __restrict__ ascale_x,
        const double* __restrict__ wscale, void* __restrict__ qkv) {
    const int which = blockIdx.x >> 3;          // 0=Q, 1=K, 2=V
    char* base = (char*)qkv + (size_t)which * 16777216;
    gemm_core(which == 0 ? xq : cq,
              wqb + (size_t)which * 1048576,
              ascale_x + (which ? NTOK : 0),
              wscale[which],
              base,
              which == 2 ? 2 : 0,
              which == 0 ? 0.18033688011112042f : 1.0f, blockIdx.x & 7, blockIdx.y);
}

__global__ __launch_bounds__(256) void gemm_o(
        const signed char* __restrict__ aq, const signed char* __restrict__ wo,
        const double* __restrict__ ascale, const double* __restrict__ wscale_p,
        float* __restrict__ out) {
    gemm_core(aq, wo, ascale, *wscale_p, out, 1, 1.0f, blockIdx.x, blockIdx.y);
}

// ---------------- MFMA flash attention v4: 16-q waves, 4 waves/SIMD ----------------
// Q/K in separate hi/lo f16 planes [b][h][t][d] (Q pre-scaled by 0.125*log2e, p=exp2);
// V packed (hi,lo) u32, transposed [b][h][d][t], loaded straight from global.
// K(t+1) prefetched into regs across lgkmcnt-only barriers (no vmcnt drain).
// 1D grid 1024: XCD swizzle keeps each bh's 32 q-blocks on one XCD (L2-resident K/V).
// Wave = 16 q x 2048 k: 4096 waves total = 4 waves/SIMD (vs 2 at 32-q waves) to
// hide exp2 chains + barrier waits. Per-q accumulation order unchanged vs v3.
#define KH_IDX(row, d8) (((row) * 8 + ((d8) ^ ((row) & 7))) * 8)       // halves

__global__ __launch_bounds__(256, 4) void attn_mfma(
        const unsigned short* __restrict__ qhg, const unsigned short* __restrict__ qlg,
        const unsigned short* __restrict__ khg, const unsigned short* __restrict__ klg,
        const unsigned* __restrict__ vg, float* __restrict__ out) {
    __shared__ __align__(16) _Float16 KhL[32 * 64];
    __shared__ __align__(16) _Float16 KlL[32 * 64];
    __shared__ __align__(16) _Float16 PhL[4][16 * 36];   // per-wave, pad-36 rows
    __shared__ __align__(16) _Float16 PlL[4][16 * 36];
    __shared__ float Lp[4][16][4];

    const int lin  = blockIdx.x;
    const int bh   = (lin & 7) * 4 + (lin >> 8);         // XCD-grouped bh (4 bh/XCD)
    const int qblk = (lin >> 3) & 31;
    const int tid  = threadIdx.x;
    const int wave = tid >> 6, lane = tid & 63;
    const int l15  = lane & 15, quad = lane >> 4;
    const int qbase = qblk * 64 + wave * 16;

    // ---- Q fragments: direct f16x8 loads from separate limb planes ----
    f16x8 qh[2], qm[2];
    #pragma unroll
    for (int c = 0; c < 2; c++) {
        size_t off = (((size_t)bh * SEQ + qbase + l15) << 6) + c * 32 + quad * 8;
        qh[c] = *(const f16x8*)(qhg + off);
        qm[c] = *(const f16x8*)(qlg + off);
    }

    floatx4 och[4] = {};   // [nh] hi-scale PV acc
    floatx4 ocm[4] = {};   // [nh] 2^-11-scale PV acc
    float lsum = 0.f;

    const unsigned short* khb = khg + ((size_t)bh * SEQ << 6);
    const unsigned short* klb = klg + ((size_t)bh * SEQ << 6);
    const unsigned* vbase = vg + ((size_t)bh << 17);       // [64][2048] words for this bh

    const int kk = tid >> 3, d8 = tid & 7;

    // prologue: prefetch K tile 0 into regs
    uint4 kh_pf = *(const uint4*)(khb + ((size_t)kk << 6) + d8 * 8);
    uint4 kl_pf = *(const uint4*)(klb + ((size_t)kk << 6) + d8 * 8);

    for (int kt = 0; kt < SEQ; kt += 32) {
        // V for this tile: issue early, consumed at PV (~full tile of latency slack)
        uint4 va[4], vb[4];
        #pragma unroll
        for (int nh = 0; nh < 4; nh++) {
            const unsigned* vp = vbase + (((size_t)(nh * 16 + l15)) << 11) + kt + quad * 8;
            va[nh] = *(const uint4*)vp;
            vb[nh] = *(const uint4*)(vp + 4);
        }

        BAR_LGKM();   // LDS from previous tile free (no vmcnt drain)

        *(uint4*)&KhL[KH_IDX(kk, d8)] = kh_pf;   // auto vmcnt wait on kh_pf only
        *(uint4*)&KlL[KH_IDX(kk, d8)] = kl_pf;

        if (kt + 32 < SEQ) {   // prefetch K(t+1): full tile latency tolerance
            kh_pf = *(const uint4*)(khb + ((size_t)(kt + 32 + kk) << 6) + d8 * 8);
            kl_pf = *(const uint4*)(klb + ((size_t)(kt + 32 + kk) << 6) + d8 * 8);
        }

        BAR_LGKM();   // staged K visible

        // K fragments (A-operand), direct f16x8 from LDS
        f16x8 kfh[2][2], kfl[2][2];
        #pragma unroll
        for (int ms = 0; ms < 2; ms++) {
            #pragma unroll
            for (int c = 0; c < 2; c++) {
                kfh[ms][c] = *(const f16x8*)&KhL[KH_IDX(ms * 16 + l15, c * 4 + quad)];
                kfl[ms][c] = *(const f16x8*)&KlL[KH_IDX(ms * 16 + l15, c * 4 + quad)];
            }
        }

        // QK -> p = exp2(s) -> P limb planes
        #pragma unroll
        for (int ms = 0; ms < 2; ms++) {
            floatx4 ah = {}, am = {};
            #pragma unroll
            for (int c = 0; c < 2; c++) {
                ah = __builtin_amdgcn_mfma_f32_16x16x32_f16(kfh[ms][c], qh[c], ah, 0, 0, 0);
                am = __builtin_amdgcn_mfma_f32_16x16x32_f16(kfh[ms][c], qm[c], am, 0, 0, 0);
                am = __builtin_amdgcn_mfma_f32_16x16x32_f16(kfl[ms][c], qh[c], am, 0, 0, 0);
            }
            float p[4];
            #pragma unroll
            for (int r = 0; r < 4; r++) {
                float s = ah[r] + am[r] * 4.8828125e-4f;
                p[r] = exp2f(s);
                lsum += p[r];
            }
            f16x4 hv, lv;
            #pragma unroll
            for (int r = 0; r < 4; r++) {
                _Float16 h = (_Float16)p[r];
                hv[r] = h;
                lv[r] = (_Float16)((p[r] - (float)h) * 2048.0f);
            }
            int poff = l15 * 36 + ms * 16 + quad * 4;
            *(f16x4*)&PhL[wave][poff] = hv;
            *(f16x4*)&PlL[wave][poff] = lv;
        }
        WAIT_LGKM();   // P writes visible to own wave's cross-lane reads

        // P fragments (A-operand) direct from limb planes; V unpack from regs; PV
        f16x8 vfh[4], vfm[4];
        #pragma unroll
        for (int nh = 0; nh < 4; nh++) {
            unsigned wd[8] = {va[nh].x, va[nh].y, va[nh].z, va[nh].w,
                              vb[nh].x, vb[nh].y, vb[nh].z, vb[nh].w};
            #pragma unroll
            for (int j = 0; j < 8; j++) { vfh[nh][j] = lo16(wd[j]); vfm[nh][j] = hi16(wd[j]); }
        }
        f16x8 pfh = *(const f16x8*)&PhL[wave][l15 * 36 + quad * 8];
        f16x8 pfm = *(const f16x8*)&PlL[wave][l15 * 36 + quad * 8];
        #pragma unroll
        for (int nh = 0; nh < 4; nh++) {
            och[nh] = __builtin_amdgcn_mfma_f32_16x16x32_f16(pfh, vfh[nh], och[nh], 0, 0, 0);
            ocm[nh] = __builtin_amdgcn_mfma_f32_16x16x32_f16(pfh, vfm[nh], ocm[nh], 0, 0, 0);
            ocm[nh] = __builtin_amdgcn_mfma_f32_16x16x32_f16(pfm, vfh[nh], ocm[nh], 0, 0, 0);
        }
    }

    // ---- epilogue: merge l across quads, normalize, write ----
    Lp[wave][l15][quad] = lsum;
    WAIT_LGKM();

    int b = bh >> 4, h = bh & 15;
    float linv[4];
    #pragma unroll
    for (int r = 0; r < 4; r++) {
        float4 lv = *(const float4*)&Lp[wave][quad * 4 + r][0];
        linv[r] = 1.0f / (lv.x + lv.y + lv.z + lv.w);
    }
    #pragma unroll
    for (int nh = 0; nh < 4; nh++) {
        #pragma unroll
        for (int r = 0; r < 4; r++) {
            int token = b * SEQ + qbase + quad * 4 + r;
            float val = (och[nh][r] + ocm[nh][r] * 4.8828125e-4f) * linv[r];
            out[(size_t)token * DM + h * 64 + nh * 16 + l15] = val;
        }
    }
}

extern "C" void kernel_launch(void* const* d_in, const int* in_sizes, int n_in,
                              void* d_out, int out_size, void* d_ws, size_t ws_size,
                              hipStream_t stream) {
    const float* x       = (const float*)d_in[0];
    const float* context = (const float*)d_in[1];
    const float* Wq      = (const float*)d_in[2];
    const float* Wk      = (const float*)d_in[3];
    const float* Wv      = (const float*)d_in[4];
    const float* Wo      = (const float*)d_in[5];
    char* ws = (char*)d_ws;

    // workspace layout (~71.4 MB). Plane region at +21102592:
    //   Qh 8MB | Ql 8MB | Kh 8MB | Kl 8MB | Vpacked 16MB  (48 MB total)
    double* wscale   = (double*)(ws + 0);            // 4 doubles
    double* partial  = (double*)(ws + 4096);         // 256 doubles
    double* ascale_x = (double*)(ws + 8192);         // 8192 doubles (x then ctx)
    double* ascale_a = (double*)(ws + 73728);        // 4096 doubles
    signed char* wqb = (signed char*)(ws + 131072);          // 4 x 1 MB int8
    signed char* xq  = (signed char*)(ws + 4325376);         // 4 MB (cq follows)
    signed char* cq  = (signed char*)(ws + 8519680);         // 4 MB
    float* attn_out  = (float*)(ws + 4325376);               // aliases xq+cq region (16 MB)
    char* planes     = ws + 21102592;                        // 48 MB limb planes
    signed char* aq  = (signed char*)(ws + 21102592);        // aliases Q planes, used after attention

    unsigned short* qhg = (unsigned short*)planes;
    unsigned short* qlg = qhg + 4194304;
    unsigned short* khg = (unsigned short*)(planes + 16777216);
    unsigned short* klg = khg + 4194304;
    unsigned*       vpg = (unsigned*)(planes + 33554432);

    wsum1<<<dim3(64, 4), 256, 0, stream>>>(Wq, Wk, Wv, Wo, partial);
    wsum2<<<1, 64, 0, stream>>>(partial, wscale);
    wquant<<<dim3(1024, 4), 256, 0, stream>>>(Wq, Wk, Wv, Wo, wscale, wqb);
    aquant2<<<2 * NTOK, 256, 0, stream>>>(x, context, xq, ascale_x);

    gemm_qkv<<<dim3(24, 32), 256, 0, stream>>>(xq, cq, wqb, ascale_x, wscale, planes);

    attn_mfma<<<dim3(1024), 256, 0, stream>>>(qhg, qlg, khg, klg, vpg, attn_out);

    aquant<<<NTOK, 256, 0, stream>>>(attn_out, aq, ascale_a);
    gemm_o<<<dim3(8, 32), 256, 0, stream>>>(aq, wqb + 3145728, ascale_a, wscale + 3, (float*)d_out);
}